// Round 1
// baseline (161.790 us; speedup 1.0000x reference)
//
#include <hip/hip_runtime.h>

// TreeCRF belief propagation, complete binary tree, 11 levels.
// emissions:   [B=2048, C=2, L=2047] f32
// transitions: [L, L, C, C] f32 (only tree edges are live: ~65 KB)
// out:         [B, C, L] f32  (class-normalized log-marginals)

#define N_LEVELS 11
#define N_LABELS 2047
#define BATCH    2048
#define NTHREADS 256

__device__ __forceinline__ float lse2(float x, float y) {
    float m = fmaxf(x, y);
    float d = fminf(x, y) - m;           // d <= 0
    return m + __logf(1.0f + __expf(d));
}

__global__ __launch_bounds__(NTHREADS) void treecrf_kernel(
    const float* __restrict__ emissions,
    const float* __restrict__ transitions,
    float* __restrict__ out)
{
    // class-major [2][2047]: lane stride-2 LDS access = 2-way aliasing = free
    __shared__ float em[2 * N_LABELS];
    __shared__ float alphas[2 * N_LABELS];
    __shared__ float betas[2 * N_LABELS];

    const int b = blockIdx.x;
    const int tid = threadIdx.x;
    const float* emg = emissions + (size_t)b * (2 * N_LABELS);
    float* outg = out + (size_t)b * (2 * N_LABELS);
    const float4* tr4 = (const float4*)transitions;  // [L][L] of float4 (cd,cs)

    // stage emissions: 4094 floats = 2047 float2 (base 16376*b bytes, 8B-aligned)
    {
        const float2* src = (const float2*)emg;
        float2* dst = (float2*)em;
        for (int i = tid; i < N_LABELS; i += NTHREADS) dst[i] = src[i];
    }
    // zero leaf alphas (nodes 1023..2046)
    for (int i = tid; i < 1024; i += NTHREADS) {
        alphas[1023 + i] = 0.f;
        alphas[N_LABELS + 1023 + i] = 0.f;
    }
    __syncthreads();

    // ---- upward sweep: compute alpha[p] from the two children ----
    for (int lvl = N_LEVELS - 2; lvl >= 0; --lvl) {
        const int base = (1 << lvl) - 1;
        const int n = 1 << lvl;
        for (int off = tid; off < n; off += NTHREADS) {
            const int p = base + off;
            const int c0 = 2 * p + 1, c1 = c0 + 1;
            const float a00 = em[c0] + alphas[c0];
            const float a01 = em[N_LABELS + c0] + alphas[N_LABELS + c0];
            const float a10 = em[c1] + alphas[c1];
            const float a11 = em[N_LABELS + c1] + alphas[N_LABELS + c1];
            // T[p, c] as float4: x=T[0][0] y=T[0][1] z=T[1][0] w=T[1][1]
            const float4 t0 = tr4[p * N_LABELS + c0];
            const float4 t1 = tr4[p * N_LABELS + c1];
            alphas[p]            = lse2(a00 + t0.x, a01 + t0.y)
                                 + lse2(a10 + t1.x, a11 + t1.y);
            alphas[N_LABELS + p] = lse2(a00 + t0.z, a01 + t0.w)
                                 + lse2(a10 + t1.z, a11 + t1.w);
        }
        __syncthreads();
    }

    // ---- root: beta = 0, emit output ----
    if (tid == 0) {
        betas[0] = 0.f; betas[N_LABELS] = 0.f;
        const float s0 = em[0] + alphas[0];
        const float s1 = em[N_LABELS] + alphas[N_LABELS];
        const float l = lse2(s0, s1);
        outg[0] = s0 - l;
        outg[N_LABELS] = s1 - l;
    }
    __syncthreads();

    // ---- downward sweep + fused epilogue ----
    for (int lvl = 1; lvl < N_LEVELS; ++lvl) {
        const int base = (1 << lvl) - 1;
        const int n = 1 << lvl;
        for (int off = tid; off < n; off += NTHREADS) {
            const int i = base + off;
            const int p = (i - 1) >> 1;
            const float b0 = em[p] + betas[p];
            const float b1 = em[N_LABELS + p] + betas[N_LABELS + p];
            const float4 t = tr4[i * N_LABELS + p];   // T[i, p][cd][cs]
            const float v0 = lse2(b0 + t.x, b1 + t.y);
            const float v1 = lse2(b0 + t.z, b1 + t.w);
            betas[i] = v0;
            betas[N_LABELS + i] = v1;
            const float s0 = em[i] + alphas[i] + v0;
            const float s1 = em[N_LABELS + i] + alphas[N_LABELS + i] + v1;
            const float l = lse2(s0, s1);
            outg[i] = s0 - l;              // coalesced across the level
            outg[N_LABELS + i] = s1 - l;
        }
        __syncthreads();
    }
}

extern "C" void kernel_launch(void* const* d_in, const int* in_sizes, int n_in,
                              void* d_out, int out_size, void* d_ws, size_t ws_size,
                              hipStream_t stream) {
    const float* emissions   = (const float*)d_in[0];
    const float* transitions = (const float*)d_in[1];
    float* out = (float*)d_out;
    treecrf_kernel<<<BATCH, NTHREADS, 0, stream>>>(emissions, transitions, out);
}

// Round 2
// 154.526 us; speedup vs baseline: 1.0470x; 1.0470x over previous
//
#include <hip/hip_runtime.h>

// TreeCRF belief propagation, complete binary tree, 11 levels, C=2.
// emissions:   [B=2048, 2, 2047] f32
// transitions: [2047, 2047, 2, 2] f32 (only the 2*2046 tree-edge float4s are live)
// out:         [B, 2, 2047] f32
//
// One block per batch element. All transition float4s a thread needs are
// prefetched into registers BEFORE the sweeps (static assignment), so the
// per-level critical path is LDS + VALU only. LDS = 2 arrays (32,752 B):
//   A[i]  = em[i] + alpha[i]
//   em[i] -> morphs into em[i] + beta[i] during the down sweep.

#define L  2047
#define NT 256

__device__ __forceinline__ float lse2(float x, float y) {
    float m = fmaxf(x, y);
    float d = fminf(x, y) - m;           // d <= 0
    return m + __logf(1.0f + __expf(d));
}

// alpha contribution + write A[p] = em[p] + alpha[p]
#define UP_NODE(p, ta, tb) do {                                             \
    const int _c0 = 2*(p) + 1;                                              \
    const float _a00 = A[_c0],     _a01 = A[L + _c0];                       \
    const float _a10 = A[_c0 + 1], _a11 = A[L + _c0 + 1];                   \
    const float _al0 = lse2(_a00 + (ta).x, _a01 + (ta).y)                   \
                     + lse2(_a10 + (tb).x, _a11 + (tb).y);                  \
    const float _al1 = lse2(_a00 + (ta).z, _a01 + (ta).w)                   \
                     + lse2(_a10 + (tb).z, _a11 + (tb).w);                  \
    A[(p)]     = em[(p)]     + _al0;                                        \
    A[L + (p)] = em[L + (p)] + _al1;                                        \
} while (0)

// beta for node i from parent's (em+beta); morph em[i] += beta; emit output
#define DN_NODE(i, t, WRITE_EM) do {                                        \
    const int _p = ((i) - 1) >> 1;                                          \
    const float _b0 = em[_p], _b1 = em[L + _p];                             \
    const float _v0 = lse2(_b0 + (t).x, _b1 + (t).y);                       \
    const float _v1 = lse2(_b0 + (t).z, _b1 + (t).w);                       \
    if (WRITE_EM) { em[(i)] += _v0; em[L + (i)] += _v1; }                   \
    const float _s0 = A[(i)] + _v0, _s1 = A[L + (i)] + _v1;                 \
    const float _l = lse2(_s0, _s1);                                        \
    outg[(i)] = _s0 - _l; outg[L + (i)] = _s1 - _l;                         \
} while (0)

__global__ __launch_bounds__(NT) void treecrf_kernel(
    const float* __restrict__ emissions,
    const float* __restrict__ transitions,
    float* __restrict__ out)
{
    __shared__ float em[2 * L];   // raw emissions; morphs to em+beta downward
    __shared__ float A[2 * L];    // em + alpha

    const int b = blockIdx.x;
    const int tid = threadIdx.x;
    const float* __restrict__ emg = emissions + (size_t)b * (2 * L);
    float* __restrict__ outg = out + (size_t)b * (2 * L);
    const float4* __restrict__ tr4 = (const float4*)transitions;

    // ---- static small-level assignment (disjoint thread ranges) ----
    // up parents, levels 7..0 -> threads [0,255); down children, levels 7..1 -> [0,254)
    int up_p = 0, dn_i = 1;
    if (tid < 128)      { up_p = 127 + tid;         dn_i = 127 + tid; }
    else if (tid < 192) { up_p = 63 + (tid - 128);  dn_i = 63 + (tid - 128); }
    else if (tid < 224) { up_p = 31 + (tid - 192);  dn_i = 31 + (tid - 192); }
    else if (tid < 240) { up_p = 15 + (tid - 224);  dn_i = 15 + (tid - 224); }
    else if (tid < 248) { up_p = 7 + (tid - 240);   dn_i = 7 + (tid - 240); }
    else if (tid < 252) { up_p = 3 + (tid - 248);   dn_i = 3 + (tid - 248); }
    else if (tid < 254) { up_p = 1 + (tid - 252);   dn_i = 1 + (tid - 252); }
    // tid 254: up level 0 (p=0). tid 255: root output. dn_i stays 1 (dummy, valid addr)

    // ---- prefetch ALL up-sweep transitions into registers ----
    float4 u9a0, u9a1, u9b0, u9b1, u8a, u8b, usa, usb;
    {
        int p = 511 + tid;                              // level 9, first parent
        const float4* q = tr4 + p * L + (2 * p + 1);
        u9a0 = q[0]; u9a1 = q[1];
        p = 767 + tid;                                  // level 9, second parent
        q = tr4 + p * L + (2 * p + 1);
        u9b0 = q[0]; u9b1 = q[1];
        p = 255 + tid;                                  // level 8
        q = tr4 + p * L + (2 * p + 1);
        u8a = q[0]; u8b = q[1];
        p = up_p;                                       // small levels 7..0
        q = tr4 + p * L + (2 * p + 1);
        usa = q[0]; usb = q[1];
    }

    // ---- stage emissions into LDS; init leaf A = em ----
    {
        const float2* __restrict__ src = (const float2*)emg;   // 8B-aligned always
        float2* dst = (float2*)em;
        #pragma unroll
        for (int k = 0; k < 8; ++k) {
            int i = tid + k * NT;
            if (i < L) dst[i] = src[i];
        }
    }
    #pragma unroll
    for (int k = 0; k < 4; ++k) {
        int i = tid + k * NT;                           // leaves 1023..2046
        A[1023 + i]     = emg[1023 + i];
        A[L + 1023 + i] = emg[L + 1023 + i];
    }
    __syncthreads();                                    // phase 1 done

    // ---- up level 9 (all threads, x2) ----
    UP_NODE(511 + tid, u9a0, u9a1);
    UP_NODE(767 + tid, u9b0, u9b1);

    // ---- prefetch ALL down-sweep transitions (latency hidden by up sweep) ----
    float4 d10a, d10b, d10c, d10d, d9a, d9b, d8, ds;
    {
        int i = 1023 + tid;        d10a = tr4[i * L + ((i - 1) >> 1)];
        i = 1279 + tid;            d10b = tr4[i * L + ((i - 1) >> 1)];
        i = 1535 + tid;            d10c = tr4[i * L + ((i - 1) >> 1)];
        i = 1791 + tid;            d10d = tr4[i * L + ((i - 1) >> 1)];
        i = 511 + tid;             d9a  = tr4[i * L + ((i - 1) >> 1)];
        i = 767 + tid;             d9b  = tr4[i * L + ((i - 1) >> 1)];
        i = 255 + tid;             d8   = tr4[i * L + ((i - 1) >> 1)];
        i = dn_i;                  ds   = tr4[i * L + ((i - 1) >> 1)];
    }
    __syncthreads();

    // ---- up level 8 ----
    UP_NODE(255 + tid, u8a, u8b);
    __syncthreads();

    // ---- up small levels 7..1 (disjoint ranges) ----
    if (tid < 128)                 UP_NODE(up_p, usa, usb);   // lvl 7
    __syncthreads();
    if (tid >= 128 && tid < 192)   UP_NODE(up_p, usa, usb);   // lvl 6
    __syncthreads();
    if (tid >= 192 && tid < 224)   UP_NODE(up_p, usa, usb);   // lvl 5
    __syncthreads();
    if (tid >= 224 && tid < 240)   UP_NODE(up_p, usa, usb);   // lvl 4
    __syncthreads();
    if (tid >= 240 && tid < 248)   UP_NODE(up_p, usa, usb);   // lvl 3
    __syncthreads();
    if (tid >= 248 && tid < 252)   UP_NODE(up_p, usa, usb);   // lvl 2
    __syncthreads();
    if (tid >= 252 && tid < 254)   UP_NODE(up_p, usa, usb);   // lvl 1
    __syncthreads();

    // ---- up level 0 (tid 254) + down level 1 (tid 252..253, indep of lvl0) ----
    if (tid == 254)                UP_NODE(0, usa, usb);
    if (tid >= 252 && tid < 254)   DN_NODE(dn_i, ds, 1);
    __syncthreads();

    // ---- root output (tid 255) + down level 2 (tid 248..251) ----
    if (tid == 255) {
        const float s0 = A[0], s1 = A[L];
        const float l = lse2(s0, s1);
        outg[0] = s0 - l; outg[L] = s1 - l;
    }
    if (tid >= 248 && tid < 252)   DN_NODE(dn_i, ds, 1);      // lvl 2
    __syncthreads();
    if (tid >= 240 && tid < 248)   DN_NODE(dn_i, ds, 1);      // lvl 3
    __syncthreads();
    if (tid >= 224 && tid < 240)   DN_NODE(dn_i, ds, 1);      // lvl 4
    __syncthreads();
    if (tid >= 192 && tid < 224)   DN_NODE(dn_i, ds, 1);      // lvl 5
    __syncthreads();
    if (tid >= 128 && tid < 192)   DN_NODE(dn_i, ds, 1);      // lvl 6
    __syncthreads();
    if (tid < 128)                 DN_NODE(dn_i, ds, 1);      // lvl 7
    __syncthreads();

    // ---- down level 8 (all) ----
    DN_NODE(255 + tid, d8, 1);
    __syncthreads();

    // ---- down level 9 (all, x2) ----
    DN_NODE(511 + tid, d9a, 1);
    DN_NODE(767 + tid, d9b, 1);
    __syncthreads();

    // ---- down level 10: leaves (no em morph needed, no trailing barrier) ----
    DN_NODE(1023 + tid, d10a, 0);
    DN_NODE(1279 + tid, d10b, 0);
    DN_NODE(1535 + tid, d10c, 0);
    DN_NODE(1791 + tid, d10d, 0);
}

extern "C" void kernel_launch(void* const* d_in, const int* in_sizes, int n_in,
                              void* d_out, int out_size, void* d_ws, size_t ws_size,
                              hipStream_t stream) {
    const float* emissions   = (const float*)d_in[0];
    const float* transitions = (const float*)d_in[1];
    float* out = (float*)d_out;
    treecrf_kernel<<<2048, NT, 0, stream>>>(emissions, transitions, out);
}

// Round 3
// 138.531 us; speedup vs baseline: 1.1679x; 1.1155x over previous
//
#include <hip/hip_runtime.h>

// TreeCRF BP, complete binary tree, 11 levels, C=2, B=2048.
// Wave-synchronous design: one 64-lane wave per batch element.
//  - lane l owns the subtree rooted at node 63+l: levels 6..10
//    (1+2+4+8+16 = 31 nodes), all state in registers.
//  - levels 5..0 via __shfl_xor butterfly (every lane redundantly carries
//    its ancestor chain -> exactly what the down sweep needs).
//  - NO LDS, NO __syncthreads. Cross-lane = shuffles only.
// Transitions (only 2*2046 edge float4s are live) are pre-packed into d_ws
// in [slot][lane] order by a tiny kernel -> all main-kernel transition
// loads are coalesced. Falls back to direct gathers if ws is too small.

#define L 2047
#define NSLOTS 78

typedef float __attribute__((ext_vector_type(4), aligned(4))) uf4;  // unaligned-ok float4
typedef float __attribute__((ext_vector_type(2), aligned(4))) uf2;

__device__ __forceinline__ float lse2(float x, float y) {
    float m = fmaxf(x, y);
    return m + __logf(1.0f + __expf(fminf(x, y) - m));
}

// parent A from two children A-values + edge transitions + parent emission
__device__ __forceinline__ void up_pair(float c00, float c01, float c10, float c11,
                                        float4 tA, float4 tB, float em0, float em1,
                                        float& o0, float& o1) {
    o0 = em0 + lse2(c00 + tA.x, c01 + tA.y) + lse2(c10 + tB.x, c11 + tB.y);
    o1 = em1 + lse2(c00 + tA.z, c01 + tA.w) + lse2(c10 + tB.z, c11 + tB.w);
}

// slot -> (dst node, src node) of the transition float4 T4[node*L + src]
__device__ __forceinline__ void slot_decode(int s, int l, int& node, int& src) {
    if (s < 16)      { int p = 511 + 8*l + (s >> 1); node = p; src = 2*p + 1 + (s & 1); }
    else if (s < 24) { int j = s - 16; int p = 255 + 4*l + (j >> 1); node = p; src = 2*p + 1 + (j & 1); }
    else if (s < 28) { int j = s - 24; int p = 127 + 2*l + (j >> 1); node = p; src = 2*p + 1 + (j & 1); }
    else if (s < 30) { int j = s - 28; int p = 63 + l; node = p; src = 2*p + 1 + j; }
    else if (s < 42) { int d = (s - 30) >> 1; int r = (s - 30) & 1;
                       int P = (1 << (5 - d)) - 1 + (l >> (d + 1)); node = P; src = 2*P + 1 + r; }
    else if (s < 47) { int t = s - 41; int n = (1 << t) - 1 + (l >> (6 - t)); node = n; src = (n - 1) >> 1; }
    else if (s < 48) { int n = 63 + l; node = n; src = (n - 1) >> 1; }
    else if (s < 50) { int j = s - 48; int n = 127 + 2*l + j; node = n; src = (n - 1) >> 1; }
    else if (s < 54) { int j = s - 50; int n = 255 + 4*l + j; node = n; src = (n - 1) >> 1; }
    else if (s < 62) { int j = s - 54; int n = 511 + 8*l + j; node = n; src = (n - 1) >> 1; }
    else             { int j = s - 62; int n = 1023 + 16*l + j; node = n; src = (n - 1) >> 1; }
}

__device__ __forceinline__ float4 ldT(const float4* __restrict__ pk,
                                      const float4* __restrict__ tr4, int s, int l) {
    if (pk) return pk[(s << 6) + l];            // coalesced, lane-major
    int n, c; slot_decode(s, l, n, c);
    return tr4[n * L + c];                       // fallback gather
}

__global__ void pack_kernel(const float4* __restrict__ tr4, float4* __restrict__ packed) {
    int idx = blockIdx.x * 256 + threadIdx.x;
    if (idx >= NSLOTS * 64) return;
    int s = idx >> 6, l = idx & 63;
    int n, c; slot_decode(s, l, n, c);
    packed[idx] = tr4[n * L + c];
}

__global__ __launch_bounds__(64) void treecrf_main(
    const float* __restrict__ emissions,
    const float4* __restrict__ pk,      // packed transitions (or nullptr)
    const float4* __restrict__ tr4,
    float* __restrict__ out)
{
    const int l = threadIdx.x;          // lane in the wave
    const int b = blockIdx.x;           // batch element
    const float* __restrict__ e0 = emissions + (size_t)b * (2 * L);
    const float* __restrict__ e1 = e0 + L;
    float* __restrict__ o0 = out + (size_t)b * (2 * L);
    float* __restrict__ o1 = o0 + L;

    // ---- leaf emissions (level 10): 16 per class, coalesced-ish vector loads
    float el0[16], el1[16];
    {
        const uf4* p0 = (const uf4*)(e0 + 1023 + 16 * l);
        const uf4* p1 = (const uf4*)(e1 + 1023 + 16 * l);
        #pragma unroll
        for (int k = 0; k < 4; ++k) {
            uf4 a = p0[k], c = p1[k];
            el0[4*k] = a.x; el0[4*k+1] = a.y; el0[4*k+2] = a.z; el0[4*k+3] = a.w;
            el1[4*k] = c.x; el1[4*k+1] = c.y; el1[4*k+2] = c.z; el1[4*k+3] = c.w;
        }
    }
    // ---- internal emissions for the lane's subtree (kept for the down sweep)
    float em9_0[8], em9_1[8], em8_0[4], em8_1[4], em7_0[2], em7_1[2], em6_0, em6_1;
    {
        const uf4* p0 = (const uf4*)(e0 + 511 + 8 * l);
        const uf4* p1 = (const uf4*)(e1 + 511 + 8 * l);
        uf4 a = p0[0], bq = p0[1], c = p1[0], d = p1[1];
        em9_0[0]=a.x; em9_0[1]=a.y; em9_0[2]=a.z; em9_0[3]=a.w;
        em9_0[4]=bq.x; em9_0[5]=bq.y; em9_0[6]=bq.z; em9_0[7]=bq.w;
        em9_1[0]=c.x; em9_1[1]=c.y; em9_1[2]=c.z; em9_1[3]=c.w;
        em9_1[4]=d.x; em9_1[5]=d.y; em9_1[6]=d.z; em9_1[7]=d.w;
        uf4 e = *(const uf4*)(e0 + 255 + 4 * l);
        uf4 f = *(const uf4*)(e1 + 255 + 4 * l);
        em8_0[0]=e.x; em8_0[1]=e.y; em8_0[2]=e.z; em8_0[3]=e.w;
        em8_1[0]=f.x; em8_1[1]=f.y; em8_1[2]=f.z; em8_1[3]=f.w;
        uf2 g = *(const uf2*)(e0 + 127 + 2 * l);
        uf2 h = *(const uf2*)(e1 + 127 + 2 * l);
        em7_0[0]=g.x; em7_0[1]=g.y; em7_1[0]=h.x; em7_1[1]=h.y;
        em6_0 = e0[63 + l]; em6_1 = e1[63 + l];
    }

    // ---- up sweep, local subtree (no cross-lane) ----
    float A9_0[8], A9_1[8];
    #pragma unroll
    for (int j = 0; j < 8; ++j) {
        float4 tA = ldT(pk, tr4, 2*j, l), tB = ldT(pk, tr4, 2*j + 1, l);
        up_pair(el0[2*j], el1[2*j], el0[2*j+1], el1[2*j+1], tA, tB,
                em9_0[j], em9_1[j], A9_0[j], A9_1[j]);
    }
    float A8_0[4], A8_1[4];
    #pragma unroll
    for (int j = 0; j < 4; ++j) {
        float4 tA = ldT(pk, tr4, 16 + 2*j, l), tB = ldT(pk, tr4, 17 + 2*j, l);
        up_pair(A9_0[2*j], A9_1[2*j], A9_0[2*j+1], A9_1[2*j+1], tA, tB,
                em8_0[j], em8_1[j], A8_0[j], A8_1[j]);
    }
    float A7_0[2], A7_1[2];
    #pragma unroll
    for (int j = 0; j < 2; ++j) {
        float4 tA = ldT(pk, tr4, 24 + 2*j, l), tB = ldT(pk, tr4, 25 + 2*j, l);
        up_pair(A8_0[2*j], A8_1[2*j], A8_0[2*j+1], A8_1[2*j+1], tA, tB,
                em7_0[j], em7_1[j], A7_0[j], A7_1[j]);
    }
    float A6_0, A6_1;
    {
        float4 tA = ldT(pk, tr4, 28, l), tB = ldT(pk, tr4, 29, l);
        up_pair(A7_0[0], A7_1[0], A7_0[1], A7_1[1], tA, tB, em6_0, em6_1, A6_0, A6_1);
    }

    // ---- up butterfly, levels 5..0 (lane carries its ancestor chain) ----
    float cur0 = A6_0, cur1 = A6_1;
    float Aa0[6], Aa1[6], Ea0[6], Ea1[6];   // indexed by parent level t = 5-d
    #pragma unroll
    for (int d = 0; d < 6; ++d) {
        const int t = 5 - d;
        const int P = (1 << t) - 1 + (l >> (d + 1));
        float p0v = __shfl_xor(cur0, 1 << d);
        float p1v = __shfl_xor(cur1, 1 << d);
        bool isL = ((l >> d) & 1) == 0;
        float L0 = isL ? cur0 : p0v, L1 = isL ? cur1 : p1v;
        float R0 = isL ? p0v : cur0, R1 = isL ? p1v : cur1;
        float4 tL = ldT(pk, tr4, 30 + 2*d, l), tR = ldT(pk, tr4, 31 + 2*d, l);
        float eP0 = e0[P], eP1 = e1[P];
        up_pair(L0, L1, R0, R1, tL, tR, eP0, eP1, cur0, cur1);
        Aa0[t] = cur0; Aa1[t] = cur1; Ea0[t] = eP0; Ea1[t] = eP1;
    }

    // ---- root output; start down sweep: D = em+beta at current ancestor ----
    if (l == 0) {
        float m = lse2(cur0, cur1);
        o0[0] = cur0 - m; o1[0] = cur1 - m;
    }
    float D0 = Ea0[0], D1 = Ea1[0];          // root: beta = 0

    // ---- down serial, levels 1..5 (each lane tracks its own ancestor path)
    #pragma unroll
    for (int t = 1; t <= 5; ++t) {
        const int n = (1 << t) - 1 + (l >> (6 - t));
        float4 td = ldT(pk, tr4, 41 + t, l);
        float b0 = lse2(D0 + td.x, D1 + td.y);
        float b1 = lse2(D0 + td.z, D1 + td.w);
        float s0 = Aa0[t] + b0, s1 = Aa1[t] + b1;
        float m = lse2(s0, s1);
        if ((l & ((1 << (6 - t)) - 1)) == 0) { o0[n] = s0 - m; o1[n] = s1 - m; }
        D0 = Ea0[t] + b0; D1 = Ea1[t] + b1;
    }

    // ---- level 6 (lane's own node) ----
    {
        float4 td = ldT(pk, tr4, 47, l);
        float b0 = lse2(D0 + td.x, D1 + td.y);
        float b1 = lse2(D0 + td.z, D1 + td.w);
        float s0 = A6_0 + b0, s1 = A6_1 + b1, m = lse2(s0, s1);
        o0[63 + l] = s0 - m; o1[63 + l] = s1 - m;
        D0 = em6_0 + b0; D1 = em6_1 + b1;
    }

    // ---- level 7 ----
    float D7_0[2], D7_1[2];
    {
        float w0[2], w1[2];
        #pragma unroll
        for (int j = 0; j < 2; ++j) {
            float4 td = ldT(pk, tr4, 48 + j, l);
            float b0 = lse2(D0 + td.x, D1 + td.y);
            float b1 = lse2(D0 + td.z, D1 + td.w);
            float s0 = A7_0[j] + b0, s1 = A7_1[j] + b1, m = lse2(s0, s1);
            w0[j] = s0 - m; w1[j] = s1 - m;
            D7_0[j] = em7_0[j] + b0; D7_1[j] = em7_1[j] + b1;
        }
        *(uf2*)(o0 + 127 + 2*l) = uf2{w0[0], w0[1]};
        *(uf2*)(o1 + 127 + 2*l) = uf2{w1[0], w1[1]};
    }

    // ---- level 8 ----
    float D8_0[4], D8_1[4];
    {
        float w0[4], w1[4];
        #pragma unroll
        for (int j = 0; j < 4; ++j) {
            float4 td = ldT(pk, tr4, 50 + j, l);
            float b0 = lse2(D7_0[j>>1] + td.x, D7_1[j>>1] + td.y);
            float b1 = lse2(D7_0[j>>1] + td.z, D7_1[j>>1] + td.w);
            float s0 = A8_0[j] + b0, s1 = A8_1[j] + b1, m = lse2(s0, s1);
            w0[j] = s0 - m; w1[j] = s1 - m;
            D8_0[j] = em8_0[j] + b0; D8_1[j] = em8_1[j] + b1;
        }
        *(uf4*)(o0 + 255 + 4*l) = uf4{w0[0], w0[1], w0[2], w0[3]};
        *(uf4*)(o1 + 255 + 4*l) = uf4{w1[0], w1[1], w1[2], w1[3]};
    }

    // ---- level 9 ----
    float D9_0[8], D9_1[8];
    {
        float w0[8], w1[8];
        #pragma unroll
        for (int j = 0; j < 8; ++j) {
            float4 td = ldT(pk, tr4, 54 + j, l);
            float b0 = lse2(D8_0[j>>1] + td.x, D8_1[j>>1] + td.y);
            float b1 = lse2(D8_0[j>>1] + td.z, D8_1[j>>1] + td.w);
            float s0 = A9_0[j] + b0, s1 = A9_1[j] + b1, m = lse2(s0, s1);
            w0[j] = s0 - m; w1[j] = s1 - m;
            D9_0[j] = em9_0[j] + b0; D9_1[j] = em9_1[j] + b1;
        }
        uf4* q0 = (uf4*)(o0 + 511 + 8*l);
        uf4* q1 = (uf4*)(o1 + 511 + 8*l);
        q0[0] = uf4{w0[0], w0[1], w0[2], w0[3]}; q0[1] = uf4{w0[4], w0[5], w0[6], w0[7]};
        q1[0] = uf4{w1[0], w1[1], w1[2], w1[3]}; q1[1] = uf4{w1[4], w1[5], w1[6], w1[7]};
    }

    // ---- level 10 (leaves): output only ----
    {
        float w0[16], w1[16];
        #pragma unroll
        for (int k = 0; k < 16; ++k) {
            float4 td = ldT(pk, tr4, 62 + k, l);
            float b0 = lse2(D9_0[k>>1] + td.x, D9_1[k>>1] + td.y);
            float b1 = lse2(D9_0[k>>1] + td.z, D9_1[k>>1] + td.w);
            float s0 = el0[k] + (A9_0[k>>1] - em9_0[k>>1], 0.f), s1; // placeholder, fixed below
            // NOTE: A at a leaf is just its emission (alpha=0): A_leaf = el.
            s0 = el0[k] + b0; s1 = el1[k] + b1;
            float m = lse2(s0, s1);
            w0[k] = s0 - m; w1[k] = s1 - m;
        }
        uf4* q0 = (uf4*)(o0 + 1023 + 16*l);
        uf4* q1 = (uf4*)(o1 + 1023 + 16*l);
        #pragma unroll
        for (int k = 0; k < 4; ++k) {
            q0[k] = uf4{w0[4*k], w0[4*k+1], w0[4*k+2], w0[4*k+3]};
            q1[k] = uf4{w1[4*k], w1[4*k+1], w1[4*k+2], w1[4*k+3]};
        }
    }
}

extern "C" void kernel_launch(void* const* d_in, const int* in_sizes, int n_in,
                              void* d_out, int out_size, void* d_ws, size_t ws_size,
                              hipStream_t stream) {
    const float* emissions = (const float*)d_in[0];
    const float4* tr4 = (const float4*)d_in[1];
    float* out = (float*)d_out;

    const size_t packed_bytes = (size_t)NSLOTS * 64 * sizeof(float4);
    const bool use_ws = (ws_size >= packed_bytes) && (d_ws != nullptr);
    float4* pk = use_ws ? (float4*)d_ws : nullptr;
    if (use_ws) {
        pack_kernel<<<(NSLOTS * 64 + 255) / 256, 256, 0, stream>>>(tr4, pk);
    }
    treecrf_main<<<2048, 64, 0, stream>>>(emissions, pk, tr4, out);
}

// Round 4
// 135.801 us; speedup vs baseline: 1.1914x; 1.0201x over previous
//
#include <hip/hip_runtime.h>

// TreeCRF BP, complete binary tree, 11 levels, C=2, B=2048.
// One 64-lane wave per batch element; 4 waves (4 batch elems) per block.
//  - lane l owns the subtree rooted at node 63+l (levels 6..10) in registers
//  - levels 5..0 via __shfl_xor butterfly
//  - live transitions pre-packed (pack_kernel) into d_ws lane-major:
//      pk[slot*64 + lane], 78 slots. Slots 0..15 (up level 9, needed first)
//      are register-prefetched; slots 16..77 are staged into LDS once per
//      block and shared by all 4 waves -> no mid-kernel global latency.

#define L 2047
#define NSLOTS 78
#define S0 16                 // first LDS-resident slot
#define NLDS (NSLOTS - S0)    // 62 slots -> 63488 B static LDS

typedef float __attribute__((ext_vector_type(4), aligned(4))) uf4;  // 4B-aligned ok
typedef float __attribute__((ext_vector_type(2), aligned(4))) uf2;

__device__ __forceinline__ float lse2(float x, float y) {
    float m = fmaxf(x, y);
    return m + __logf(1.0f + __expf(fminf(x, y) - m));
}

__device__ __forceinline__ void up_pair(float c00, float c01, float c10, float c11,
                                        float4 tA, float4 tB, float em0, float em1,
                                        float& o0, float& o1) {
    o0 = em0 + lse2(c00 + tA.x, c01 + tA.y) + lse2(c10 + tB.x, c11 + tB.y);
    o1 = em1 + lse2(c00 + tA.z, c01 + tA.w) + lse2(c10 + tB.z, c11 + tB.w);
}

// slot -> (dst node, src node) of the live transition float4 tr4[node*L + src]
__device__ __forceinline__ void slot_decode(int s, int l, int& node, int& src) {
    if (s < 16)      { int p = 511 + 8*l + (s >> 1); node = p; src = 2*p + 1 + (s & 1); }
    else if (s < 24) { int j = s - 16; int p = 255 + 4*l + (j >> 1); node = p; src = 2*p + 1 + (j & 1); }
    else if (s < 28) { int j = s - 24; int p = 127 + 2*l + (j >> 1); node = p; src = 2*p + 1 + (j & 1); }
    else if (s < 30) { int j = s - 28; int p = 63 + l; node = p; src = 2*p + 1 + j; }
    else if (s < 42) { int d = (s - 30) >> 1; int r = (s - 30) & 1;
                       int P = (1 << (5 - d)) - 1 + (l >> (d + 1)); node = P; src = 2*P + 1 + r; }
    else if (s < 47) { int t = s - 41; int n = (1 << t) - 1 + (l >> (6 - t)); node = n; src = (n - 1) >> 1; }
    else if (s < 48) { int n = 63 + l; node = n; src = (n - 1) >> 1; }
    else if (s < 50) { int j = s - 48; int n = 127 + 2*l + j; node = n; src = (n - 1) >> 1; }
    else if (s < 54) { int j = s - 50; int n = 255 + 4*l + j; node = n; src = (n - 1) >> 1; }
    else if (s < 62) { int j = s - 54; int n = 511 + 8*l + j; node = n; src = (n - 1) >> 1; }
    else             { int j = s - 62; int n = 1023 + 16*l + j; node = n; src = (n - 1) >> 1; }
}

__global__ void pack_kernel(const float4* __restrict__ tr4, float4* __restrict__ packed) {
    int idx = blockIdx.x * 256 + threadIdx.x;
    if (idx >= NSLOTS * 64) return;
    int s = idx >> 6, l = idx & 63;
    int n, c; slot_decode(s, l, n, c);
    packed[idx] = tr4[n * L + c];
}

__global__ __launch_bounds__(256) void treecrf_main(
    const float* __restrict__ emissions,
    const float4* __restrict__ pk,      // packed transitions (or nullptr)
    const float4* __restrict__ tr4,     // fallback source
    float* __restrict__ out)
{
    __shared__ float4 lt[NLDS * 64];    // slots 16..77, lane-major

    const int tid = threadIdx.x;
    const int l = tid & 63;             // lane
    const int b = blockIdx.x * 4 + (tid >> 6);
    const float* __restrict__ e0 = emissions + (size_t)b * (2 * L);
    const float* __restrict__ e1 = e0 + L;
    float* __restrict__ o0 = out + (size_t)b * (2 * L);
    float* __restrict__ o1 = o0 + L;

    // ---- stage slots 16..77 into LDS (whole block cooperates) ----
    if (pk) {
        #pragma unroll
        for (int k = 0; k < 16; ++k) {
            int i = tid + k * 256;
            if (i < NLDS * 64) lt[i] = pk[S0 * 64 + i];
        }
    } else {
        for (int i = tid; i < NLDS * 64; i += 256) {
            int n, c; slot_decode(S0 + (i >> 6), i & 63, n, c);
            lt[i] = tr4[n * L + c];
        }
    }
    #define LT(s) lt[(((s) - S0) << 6) + l]

    // ---- register prefetch: up level-9 transitions (slots 0..15) ----
    float4 t9[16];
    if (pk) {
        #pragma unroll
        for (int k = 0; k < 16; ++k) t9[k] = pk[(k << 6) + l];
    } else {
        #pragma unroll
        for (int k = 0; k < 16; ++k) {
            int n, c; slot_decode(k, l, n, c);
            t9[k] = tr4[n * L + c];
        }
    }

    // ---- emissions: leaves + lane's internal subtree ----
    float el0[16], el1[16];
    {
        const uf4* p0 = (const uf4*)(e0 + 1023 + 16 * l);
        const uf4* p1 = (const uf4*)(e1 + 1023 + 16 * l);
        #pragma unroll
        for (int k = 0; k < 4; ++k) {
            uf4 a = p0[k], c = p1[k];
            el0[4*k] = a.x; el0[4*k+1] = a.y; el0[4*k+2] = a.z; el0[4*k+3] = a.w;
            el1[4*k] = c.x; el1[4*k+1] = c.y; el1[4*k+2] = c.z; el1[4*k+3] = c.w;
        }
    }
    float em9_0[8], em9_1[8], em8_0[4], em8_1[4], em7_0[2], em7_1[2], em6_0, em6_1;
    {
        const uf4* p0 = (const uf4*)(e0 + 511 + 8 * l);
        const uf4* p1 = (const uf4*)(e1 + 511 + 8 * l);
        uf4 a = p0[0], bq = p0[1], c = p1[0], d = p1[1];
        em9_0[0]=a.x; em9_0[1]=a.y; em9_0[2]=a.z; em9_0[3]=a.w;
        em9_0[4]=bq.x; em9_0[5]=bq.y; em9_0[6]=bq.z; em9_0[7]=bq.w;
        em9_1[0]=c.x; em9_1[1]=c.y; em9_1[2]=c.z; em9_1[3]=c.w;
        em9_1[4]=d.x; em9_1[5]=d.y; em9_1[6]=d.z; em9_1[7]=d.w;
        uf4 e = *(const uf4*)(e0 + 255 + 4 * l);
        uf4 f = *(const uf4*)(e1 + 255 + 4 * l);
        em8_0[0]=e.x; em8_0[1]=e.y; em8_0[2]=e.z; em8_0[3]=e.w;
        em8_1[0]=f.x; em8_1[1]=f.y; em8_1[2]=f.z; em8_1[3]=f.w;
        uf2 g = *(const uf2*)(e0 + 127 + 2 * l);
        uf2 h = *(const uf2*)(e1 + 127 + 2 * l);
        em7_0[0]=g.x; em7_0[1]=g.y; em7_1[0]=h.x; em7_1[1]=h.y;
        em6_0 = e0[63 + l]; em6_1 = e1[63 + l];
    }
    // ---- ancestor emissions (levels 0..5), prefetched for butterfly+down ----
    float Ea0[6], Ea1[6];
    #pragma unroll
    for (int t = 0; t <= 5; ++t) {
        const int P = (1 << t) - 1 + (l >> (6 - t));
        Ea0[t] = e0[P]; Ea1[t] = e1[P];
    }

    // ---- up level 9 (register transitions, no LDS dependency) ----
    float A9_0[8], A9_1[8];
    #pragma unroll
    for (int j = 0; j < 8; ++j)
        up_pair(el0[2*j], el1[2*j], el0[2*j+1], el1[2*j+1], t9[2*j], t9[2*j+1],
                em9_0[j], em9_1[j], A9_0[j], A9_1[j]);

    __syncthreads();   // LDS transitions ready

    // ---- up levels 8..6 (local subtree) ----
    float A8_0[4], A8_1[4];
    #pragma unroll
    for (int j = 0; j < 4; ++j)
        up_pair(A9_0[2*j], A9_1[2*j], A9_0[2*j+1], A9_1[2*j+1],
                LT(16 + 2*j), LT(17 + 2*j), em8_0[j], em8_1[j], A8_0[j], A8_1[j]);
    float A7_0[2], A7_1[2];
    #pragma unroll
    for (int j = 0; j < 2; ++j)
        up_pair(A8_0[2*j], A8_1[2*j], A8_0[2*j+1], A8_1[2*j+1],
                LT(24 + 2*j), LT(25 + 2*j), em7_0[j], em7_1[j], A7_0[j], A7_1[j]);
    float A6_0, A6_1;
    up_pair(A7_0[0], A7_1[0], A7_0[1], A7_1[1], LT(28), LT(29), em6_0, em6_1, A6_0, A6_1);

    // ---- up butterfly, levels 5..0 ----
    float cur0 = A6_0, cur1 = A6_1;
    float Aa0[6], Aa1[6];
    #pragma unroll
    for (int d = 0; d < 6; ++d) {
        const int t = 5 - d;
        float p0v = __shfl_xor(cur0, 1 << d);
        float p1v = __shfl_xor(cur1, 1 << d);
        bool isL = ((l >> d) & 1) == 0;
        float Lc0 = isL ? cur0 : p0v, Lc1 = isL ? cur1 : p1v;
        float Rc0 = isL ? p0v : cur0, Rc1 = isL ? p1v : cur1;
        float4 tL = LT(30 + 2*d), tR = LT(31 + 2*d);
        up_pair(Lc0, Lc1, Rc0, Rc1, tL, tR, Ea0[t], Ea1[t], cur0, cur1);
        Aa0[t] = cur0; Aa1[t] = cur1;
    }

    // ---- root output; start down sweep ----
    if (l == 0) {
        float m = lse2(cur0, cur1);
        o0[0] = cur0 - m; o1[0] = cur1 - m;
    }
    float D0 = Ea0[0], D1 = Ea1[0];      // root: em + beta(=0)

    // ---- down levels 1..5 (per-lane ancestor path) ----
    #pragma unroll
    for (int t = 1; t <= 5; ++t) {
        const int n = (1 << t) - 1 + (l >> (6 - t));
        float4 td = LT(41 + t);
        float b0 = lse2(D0 + td.x, D1 + td.y);
        float b1 = lse2(D0 + td.z, D1 + td.w);
        float s0 = Aa0[t] + b0, s1 = Aa1[t] + b1, m = lse2(s0, s1);
        if ((l & ((1 << (6 - t)) - 1)) == 0) { o0[n] = s0 - m; o1[n] = s1 - m; }
        D0 = Ea0[t] + b0; D1 = Ea1[t] + b1;
    }

    // ---- level 6 ----
    {
        float4 td = LT(47);
        float b0 = lse2(D0 + td.x, D1 + td.y);
        float b1 = lse2(D0 + td.z, D1 + td.w);
        float s0 = A6_0 + b0, s1 = A6_1 + b1, m = lse2(s0, s1);
        o0[63 + l] = s0 - m; o1[63 + l] = s1 - m;
        D0 = em6_0 + b0; D1 = em6_1 + b1;
    }

    // ---- level 7 ----
    float D7_0[2], D7_1[2];
    {
        float w0[2], w1[2];
        #pragma unroll
        for (int j = 0; j < 2; ++j) {
            float4 td = LT(48 + j);
            float b0 = lse2(D0 + td.x, D1 + td.y);
            float b1 = lse2(D0 + td.z, D1 + td.w);
            float s0 = A7_0[j] + b0, s1 = A7_1[j] + b1, m = lse2(s0, s1);
            w0[j] = s0 - m; w1[j] = s1 - m;
            D7_0[j] = em7_0[j] + b0; D7_1[j] = em7_1[j] + b1;
        }
        *(uf2*)(o0 + 127 + 2*l) = uf2{w0[0], w0[1]};
        *(uf2*)(o1 + 127 + 2*l) = uf2{w1[0], w1[1]};
    }

    // ---- level 8 ----
    float D8_0[4], D8_1[4];
    {
        float w0[4], w1[4];
        #pragma unroll
        for (int j = 0; j < 4; ++j) {
            float4 td = LT(50 + j);
            float b0 = lse2(D7_0[j>>1] + td.x, D7_1[j>>1] + td.y);
            float b1 = lse2(D7_0[j>>1] + td.z, D7_1[j>>1] + td.w);
            float s0 = A8_0[j] + b0, s1 = A8_1[j] + b1, m = lse2(s0, s1);
            w0[j] = s0 - m; w1[j] = s1 - m;
            D8_0[j] = em8_0[j] + b0; D8_1[j] = em8_1[j] + b1;
        }
        *(uf4*)(o0 + 255 + 4*l) = uf4{w0[0], w0[1], w0[2], w0[3]};
        *(uf4*)(o1 + 255 + 4*l) = uf4{w1[0], w1[1], w1[2], w1[3]};
    }

    // ---- level 9 ----
    float D9_0[8], D9_1[8];
    {
        float w0[8], w1[8];
        #pragma unroll
        for (int j = 0; j < 8; ++j) {
            float4 td = LT(54 + j);
            float b0 = lse2(D8_0[j>>1] + td.x, D8_1[j>>1] + td.y);
            float b1 = lse2(D8_0[j>>1] + td.z, D8_1[j>>1] + td.w);
            float s0 = A9_0[j] + b0, s1 = A9_1[j] + b1, m = lse2(s0, s1);
            w0[j] = s0 - m; w1[j] = s1 - m;
            D9_0[j] = em9_0[j] + b0; D9_1[j] = em9_1[j] + b1;
        }
        uf4* q0 = (uf4*)(o0 + 511 + 8*l);
        uf4* q1 = (uf4*)(o1 + 511 + 8*l);
        q0[0] = uf4{w0[0], w0[1], w0[2], w0[3]}; q0[1] = uf4{w0[4], w0[5], w0[6], w0[7]};
        q1[0] = uf4{w1[0], w1[1], w1[2], w1[3]}; q1[1] = uf4{w1[4], w1[5], w1[6], w1[7]};
    }

    // ---- level 10 (leaves; alpha at a leaf is 0 so A_leaf = el) ----
    {
        float w0[16], w1[16];
        #pragma unroll
        for (int k = 0; k < 16; ++k) {
            float4 td = LT(62 + k);
            float b0 = lse2(D9_0[k>>1] + td.x, D9_1[k>>1] + td.y);
            float b1 = lse2(D9_0[k>>1] + td.z, D9_1[k>>1] + td.w);
            float s0 = el0[k] + b0, s1 = el1[k] + b1, m = lse2(s0, s1);
            w0[k] = s0 - m; w1[k] = s1 - m;
        }
        uf4* q0 = (uf4*)(o0 + 1023 + 16*l);
        uf4* q1 = (uf4*)(o1 + 1023 + 16*l);
        #pragma unroll
        for (int k = 0; k < 4; ++k) {
            q0[k] = uf4{w0[4*k], w0[4*k+1], w0[4*k+2], w0[4*k+3]};
            q1[k] = uf4{w1[4*k], w1[4*k+1], w1[4*k+2], w1[4*k+3]};
        }
    }
    #undef LT
}

extern "C" void kernel_launch(void* const* d_in, const int* in_sizes, int n_in,
                              void* d_out, int out_size, void* d_ws, size_t ws_size,
                              hipStream_t stream) {
    const float* emissions = (const float*)d_in[0];
    const float4* tr4 = (const float4*)d_in[1];
    float* out = (float*)d_out;

    const size_t packed_bytes = (size_t)NSLOTS * 64 * sizeof(float4);
    const bool use_ws = (ws_size >= packed_bytes) && (d_ws != nullptr);
    float4* pk = use_ws ? (float4*)d_ws : nullptr;
    if (use_ws)
        pack_kernel<<<(NSLOTS * 64 + 255) / 256, 256, 0, stream>>>(tr4, pk);
    treecrf_main<<<512, 256, 0, stream>>>(emissions, pk, tr4, out);
}

// Round 5
// 133.539 us; speedup vs baseline: 1.2116x; 1.0169x over previous
//
#include <hip/hip_runtime.h>

// TreeCRF BP, complete binary tree, 11 levels, C=2, B=2048.
// Round 5: split each batch's tree across TWO waves (4096 waves total) to
// double parallelism and halve per-wave program length.
//  - block = 128 threads = 2 waves = 1 batch element. wave r owns the half
//    tree below root child (1+r); lane l owns the 15-node subtree under
//    level-7 node 127+64r+l (8 leaves), levels 6..1 via __shfl_xor butterfly.
//  - root combine crosses waves via 16 B LDS + one barrier.
//  - transitions: 2*49 live float4 slots per (role,lane), pre-packed
//    lane-major into d_ws (100 KB, L2-resident) -> coalesced flow loads.
//  - __launch_bounds__(128,4): target <=128 VGPR -> 16 waves/CU, all
//    co-resident in a single round.

#define L 2047
#define NSLOT 49
#define PK_ELEMS (2 * NSLOT * 64)

typedef float __attribute__((ext_vector_type(4), aligned(4))) uf4;  // 4B-align ok
typedef float __attribute__((ext_vector_type(2), aligned(4))) uf2;

__device__ __forceinline__ float lse2(float x, float y) {
    float m = fmaxf(x, y);
    return m + __logf(1.0f + __expf(fminf(x, y) - m));
}

__device__ __forceinline__ void up_pair(float c00, float c01, float c10, float c11,
                                        float4 tA, float4 tB, float em0, float em1,
                                        float& o0, float& o1) {
    o0 = em0 + lse2(c00 + tA.x, c01 + tA.y) + lse2(c10 + tB.x, c11 + tB.y);
    o1 = em1 + lse2(c00 + tA.z, c01 + tA.w) + lse2(c10 + tB.z, c11 + tB.w);
}

// (role, slot, lane) -> (dst node, src node): transition float4 tr4[dst*L+src]
__device__ __forceinline__ void slot_decode(int r, int s, int l, int& dst, int& src) {
    const int n7 = 127 + 64 * r + l;
    if (s < 8)       { int k = s >> 1;      dst = 4*n7 + 3 + k;         src = 2*dst + 1 + (s & 1); }
    else if (s < 12) { int j = (s - 8) >> 1;dst = 2*n7 + 1 + j;         src = 2*dst + 1 + (s & 1); }
    else if (s < 14) {                      dst = n7;                   src = 2*n7 + 1 + (s - 12); }
    else if (s < 26) { int d = (s - 14) >> 1; dst = ((n7+1) >> (d+1)) - 1; src = 2*dst + 1 + (s & 1); }
    else if (s < 28) {                      dst = 0;                    src = 1 + (s - 26); }
    else if (s < 34) { int t = s - 27;      dst = ((n7+1) >> (7-t)) - 1; src = (dst - 1) >> 1; }
    else if (s < 35) {                      dst = n7;                   src = (n7 - 1) >> 1; }
    else if (s < 37) {                      dst = 2*n7 + 1 + (s - 35);  src = n7; }
    else if (s < 41) {                      dst = 4*n7 + 3 + (s - 37);  src = (dst - 1) >> 1; }
    else             {                      dst = 8*n7 + 7 + (s - 41);  src = (dst - 1) >> 1; }
}

__global__ void pack_kernel(const float4* __restrict__ tr4, float4* __restrict__ pk) {
    int idx = blockIdx.x * 256 + threadIdx.x;
    if (idx >= PK_ELEMS) return;
    int r = idx / (NSLOT * 64);
    int rem = idx - r * (NSLOT * 64);
    int s = rem >> 6, l = rem & 63;
    int d_, c_; slot_decode(r, s, l, d_, c_);
    pk[idx] = tr4[d_ * L + c_];
}

template <bool UPK>
__global__ __launch_bounds__(128, 4) void treecrf_main(
    const float* __restrict__ emissions,
    const float4* __restrict__ pk,
    const float4* __restrict__ tr4,
    float* __restrict__ out)
{
    __shared__ float sh[4];
    const int tid = threadIdx.x;
    const int l = tid & 63;
    const int r = tid >> 6;                // wave role: half-tree under node 1+r
    const int b = blockIdx.x;
    const float* __restrict__ e0 = emissions + (size_t)b * (2 * L);
    const float* __restrict__ e1 = e0 + L;
    float* __restrict__ o0 = out + (size_t)b * (2 * L);
    float* __restrict__ o1 = o0 + L;

    auto FL = [&](int s) -> float4 {
        if (UPK) return pk[((r * NSLOT + s) << 6) + l];
        int d_, c_; slot_decode(r, s, l, d_, c_);
        return tr4[d_ * L + c_];
    };

    // ---- emissions ----
    float el0[8], el1[8];                                  // leaves 8n7+7+m
    {
        const uf4* p0 = (const uf4*)(e0 + 1023 + 512*r + 8*l);
        const uf4* p1 = (const uf4*)(e1 + 1023 + 512*r + 8*l);
        uf4 a = p0[0], c = p0[1], d = p1[0], e = p1[1];
        el0[0]=a.x; el0[1]=a.y; el0[2]=a.z; el0[3]=a.w;
        el0[4]=c.x; el0[5]=c.y; el0[6]=c.z; el0[7]=c.w;
        el1[0]=d.x; el1[1]=d.y; el1[2]=d.z; el1[3]=d.w;
        el1[4]=e.x; el1[5]=e.y; el1[6]=e.z; el1[7]=e.w;
    }
    float em9_0[4], em9_1[4], em8_0[2], em8_1[2], em7_0, em7_1;
    {
        uf4 a = *(const uf4*)(e0 + 511 + 256*r + 4*l);
        uf4 c = *(const uf4*)(e1 + 511 + 256*r + 4*l);
        em9_0[0]=a.x; em9_0[1]=a.y; em9_0[2]=a.z; em9_0[3]=a.w;
        em9_1[0]=c.x; em9_1[1]=c.y; em9_1[2]=c.z; em9_1[3]=c.w;
        uf2 g = *(const uf2*)(e0 + 255 + 128*r + 2*l);
        uf2 h = *(const uf2*)(e1 + 255 + 128*r + 2*l);
        em8_0[0]=g.x; em8_0[1]=g.y; em8_1[0]=h.x; em8_1[1]=h.y;
        em7_0 = e0[127 + 64*r + l]; em7_1 = e1[127 + 64*r + l];
    }
    float Ea0[7], Ea1[7];                                  // [0]=root, [t]=ancestor lvl t
    Ea0[0] = e0[0]; Ea1[0] = e1[0];
    #pragma unroll
    for (int t = 1; t <= 6; ++t) {
        const int n = ((128 + 64*r + l) >> (7 - t)) - 1;
        Ea0[t] = e0[n]; Ea1[t] = e1[n];
    }

    // ---- up: local subtree (levels 10->7) ----
    float A9_0[4], A9_1[4];
    #pragma unroll
    for (int k = 0; k < 4; ++k)
        up_pair(el0[2*k], el1[2*k], el0[2*k+1], el1[2*k+1], FL(2*k), FL(2*k+1),
                em9_0[k], em9_1[k], A9_0[k], A9_1[k]);
    float A8_0[2], A8_1[2];
    #pragma unroll
    for (int j = 0; j < 2; ++j)
        up_pair(A9_0[2*j], A9_1[2*j], A9_0[2*j+1], A9_1[2*j+1], FL(8+2*j), FL(9+2*j),
                em8_0[j], em8_1[j], A8_0[j], A8_1[j]);
    float A7_0, A7_1;
    up_pair(A8_0[0], A8_1[0], A8_0[1], A8_1[1], FL(12), FL(13), em7_0, em7_1, A7_0, A7_1);

    // ---- up butterfly: levels 6..1 within the wave ----
    float cur0 = A7_0, cur1 = A7_1;
    float Aa0[7], Aa1[7];                                  // [t]=A at ancestor lvl t
    #pragma unroll
    for (int d = 0; d < 6; ++d) {
        const int t = 6 - d;
        float p0v = __shfl_xor(cur0, 1 << d);
        float p1v = __shfl_xor(cur1, 1 << d);
        bool isL = ((l >> d) & 1) == 0;
        float Lc0 = isL ? cur0 : p0v, Lc1 = isL ? cur1 : p1v;
        float Rc0 = isL ? p0v : cur0, Rc1 = isL ? p1v : cur1;
        up_pair(Lc0, Lc1, Rc0, Rc1, FL(14 + 2*d), FL(15 + 2*d),
                Ea0[t], Ea1[t], cur0, cur1);
        Aa0[t] = cur0; Aa1[t] = cur1;
    }

    // ---- root combine across waves (16 B LDS handoff) ----
    if (l == 0) { sh[2*r] = cur0; sh[2*r + 1] = cur1; }
    __syncthreads();
    {
        float a1_0 = sh[0], a1_1 = sh[1], a2_0 = sh[2], a2_1 = sh[3];
        float4 t1 = FL(26), t2 = FL(27);
        float AR0 = Ea0[0] + lse2(a1_0 + t1.x, a1_1 + t1.y)
                           + lse2(a2_0 + t2.x, a2_1 + t2.y);
        float AR1 = Ea1[0] + lse2(a1_0 + t1.z, a1_1 + t1.w)
                           + lse2(a2_0 + t2.z, a2_1 + t2.w);
        if (r == 0 && l == 0) {
            float m = lse2(AR0, AR1);
            o0[0] = AR0 - m; o1[0] = AR1 - m;
        }
    }

    // ---- down: ancestor chain levels 1..6 ----
    float D0 = Ea0[0], D1 = Ea1[0];                        // root em + beta(=0)
    #pragma unroll
    for (int t = 1; t <= 6; ++t) {
        float4 td = FL(27 + t);
        float b0 = lse2(D0 + td.x, D1 + td.y);
        float b1 = lse2(D0 + td.z, D1 + td.w);
        float s0 = Aa0[t] + b0, s1 = Aa1[t] + b1, m = lse2(s0, s1);
        if ((l & ((1 << (7 - t)) - 1)) == 0) {
            const int n = ((128 + 64*r + l) >> (7 - t)) - 1;
            o0[n] = s0 - m; o1[n] = s1 - m;
        }
        D0 = Ea0[t] + b0; D1 = Ea1[t] + b1;
    }

    // ---- level 7 (own node) ----
    {
        float4 td = FL(34);
        float b0 = lse2(D0 + td.x, D1 + td.y);
        float b1 = lse2(D0 + td.z, D1 + td.w);
        float s0 = A7_0 + b0, s1 = A7_1 + b1, m = lse2(s0, s1);
        o0[127 + 64*r + l] = s0 - m; o1[127 + 64*r + l] = s1 - m;
        D0 = em7_0 + b0; D1 = em7_1 + b1;
    }

    // ---- level 8 ----
    float D8_0[2], D8_1[2];
    {
        float w0[2], w1[2];
        #pragma unroll
        for (int j = 0; j < 2; ++j) {
            float4 td = FL(35 + j);
            float b0 = lse2(D0 + td.x, D1 + td.y);
            float b1 = lse2(D0 + td.z, D1 + td.w);
            float s0 = A8_0[j] + b0, s1 = A8_1[j] + b1, m = lse2(s0, s1);
            w0[j] = s0 - m; w1[j] = s1 - m;
            D8_0[j] = em8_0[j] + b0; D8_1[j] = em8_1[j] + b1;
        }
        *(uf2*)(o0 + 255 + 128*r + 2*l) = uf2{w0[0], w0[1]};
        *(uf2*)(o1 + 255 + 128*r + 2*l) = uf2{w1[0], w1[1]};
    }

    // ---- level 9 ----
    float D9_0[4], D9_1[4];
    {
        float w0[4], w1[4];
        #pragma unroll
        for (int k = 0; k < 4; ++k) {
            float4 td = FL(37 + k);
            float b0 = lse2(D8_0[k>>1] + td.x, D8_1[k>>1] + td.y);
            float b1 = lse2(D8_0[k>>1] + td.z, D8_1[k>>1] + td.w);
            float s0 = A9_0[k] + b0, s1 = A9_1[k] + b1, m = lse2(s0, s1);
            w0[k] = s0 - m; w1[k] = s1 - m;
            D9_0[k] = em9_0[k] + b0; D9_1[k] = em9_1[k] + b1;
        }
        *(uf4*)(o0 + 511 + 256*r + 4*l) = uf4{w0[0], w0[1], w0[2], w0[3]};
        *(uf4*)(o1 + 511 + 256*r + 4*l) = uf4{w1[0], w1[1], w1[2], w1[3]};
    }

    // ---- level 10 (leaves; A_leaf = emission) ----
    {
        float w0[8], w1[8];
        #pragma unroll
        for (int m2 = 0; m2 < 8; ++m2) {
            float4 td = FL(41 + m2);
            float b0 = lse2(D9_0[m2>>1] + td.x, D9_1[m2>>1] + td.y);
            float b1 = lse2(D9_0[m2>>1] + td.z, D9_1[m2>>1] + td.w);
            float s0 = el0[m2] + b0, s1 = el1[m2] + b1, m = lse2(s0, s1);
            w0[m2] = s0 - m; w1[m2] = s1 - m;
        }
        uf4* q0 = (uf4*)(o0 + 1023 + 512*r + 8*l);
        uf4* q1 = (uf4*)(o1 + 1023 + 512*r + 8*l);
        q0[0] = uf4{w0[0], w0[1], w0[2], w0[3]}; q0[1] = uf4{w0[4], w0[5], w0[6], w0[7]};
        q1[0] = uf4{w1[0], w1[1], w1[2], w1[3]}; q1[1] = uf4{w1[4], w1[5], w1[6], w1[7]};
    }
}

extern "C" void kernel_launch(void* const* d_in, const int* in_sizes, int n_in,
                              void* d_out, int out_size, void* d_ws, size_t ws_size,
                              hipStream_t stream) {
    const float* emissions = (const float*)d_in[0];
    const float4* tr4 = (const float4*)d_in[1];
    float* out = (float*)d_out;

    const size_t packed_bytes = (size_t)PK_ELEMS * sizeof(float4);   // ~100 KB
    const bool use_ws = (ws_size >= packed_bytes) && (d_ws != nullptr);
    if (use_ws) {
        float4* pk = (float4*)d_ws;
        pack_kernel<<<(PK_ELEMS + 255) / 256, 256, 0, stream>>>(tr4, pk);
        treecrf_main<true><<<2048, 128, 0, stream>>>(emissions, pk, tr4, out);
    } else {
        treecrf_main<false><<<2048, 128, 0, stream>>>(emissions, nullptr, tr4, out);
    }
}